// Round 1
// baseline (516.734 us; speedup 1.0000x reference)
//
#include <hip/hip_runtime.h>
#include <hip/hip_bf16.h>

// MeshConv: gather(self+4 neighbors) -> conv1d(k=5) -> BatchNorm(train) -> ReLU
// Strategy:
//  - bias b cancels in BN (mu absorbs it, var shift-invariant) -> ignored
//  - cast x and W to bf16 -> MFMA 16x16x32; bf16 x copy (128MB) is L3-resident
//  - pass1: conv + per-channel sum/sumsq (block reduce + atomics)
//  - pass2: recompute conv, apply scale/shift, relu, store
//  - e2e may arrive int32 or int64 (JAX x64 ambiguity) -> on-device detection

typedef short bf16x8 __attribute__((ext_vector_type(8)));
typedef float f32x4  __attribute__((ext_vector_type(4)));
typedef int   i32x4  __attribute__((ext_vector_type(4)));

__device__ __forceinline__ unsigned short f2bf(float f) {
    unsigned u = __float_as_uint(f);
    u += 0x7fffu + ((u >> 16) & 1u);   // RNE
    return (unsigned short)(u >> 16);
}

// ---- prep: zero stats, detect e2e element width ----------------------------
__global__ void k_prep(const int* __restrict__ e2e, float* __restrict__ stats,
                       int* __restrict__ flag) {
    __shared__ int sOr;
    if (threadIdx.x == 0) sOr = 0;
    __syncthreads();
    int o = 0;
    for (int j = threadIdx.x; j < 1024; j += blockDim.x)
        o |= e2e[2 * j + 1];           // high words if int64, random ids if int32
    if (o) atomicOr(&sOr, 1);
    if (threadIdx.x < 256) stats[threadIdx.x] = 0.0f;
    __syncthreads();
    if (threadIdx.x == 0) *flag = (sOr == 0) ? 1 : 0;   // 1 => int64
}

// ---- pack W[o][c][k5] into B-fragment order, bf16 --------------------------
// Wf slot g = (t*8 + nt)*64 + lane, 8 bf16 each:
//   j -> W[o = nt*16 + (lane&15)][c = (t&1)*32 + (lane>>4)*8 + j][k5 = t>>1]
__global__ void k_wpack(const float* __restrict__ W, short* __restrict__ wf) {
    int g = blockIdx.x * blockDim.x + threadIdx.x;
    if (g >= 5120) return;
    int lane = g & 63, nt = (g >> 6) & 7, t = g >> 9;
    int o  = nt * 16 + (lane & 15);
    int c0 = (t & 1) * 32 + (lane >> 4) * 8;
    int k5 = t >> 1;
    bf16x8 v;
#pragma unroll
    for (int j = 0; j < 8; ++j)
        v[j] = (short)f2bf(W[(o * 64 + c0 + j) * 5 + k5]);
    ((bf16x8*)wf)[g] = v;
}

// ---- x fp32 -> bf16 --------------------------------------------------------
__global__ void k_convert(const float* __restrict__ x, short* __restrict__ xb, int n8) {
    int i = blockIdx.x * blockDim.x + threadIdx.x;
    int stride = gridDim.x * blockDim.x;
    for (; i < n8; i += stride) {
        const f32x4* p = (const f32x4*)(x + (size_t)i * 8);
        f32x4 a = p[0], b = p[1];
        bf16x8 o;
        o[0] = (short)f2bf(a[0]); o[1] = (short)f2bf(a[1]);
        o[2] = (short)f2bf(a[2]); o[3] = (short)f2bf(a[3]);
        o[4] = (short)f2bf(b[0]); o[5] = (short)f2bf(b[1]);
        o[6] = (short)f2bf(b[2]); o[7] = (short)f2bf(b[3]);
        ((bf16x8*)xb)[i] = o;
    }
}

// ---- finalize: scale/shift from stats --------------------------------------
__global__ void k_finalize(const float* __restrict__ stats, const float* __restrict__ gamma,
                           const float* __restrict__ beta, float* __restrict__ ss, int E) {
    int c = threadIdx.x;
    if (c < 128) {
        float inv = 1.0f / (float)E;
        float mu  = stats[c] * inv;
        float var = stats[128 + c] * inv - mu * mu;
        float sc  = gamma[c] * rsqrtf(var + 1e-5f);
        ss[c]       = sc;
        ss[128 + c] = beta[c] - mu * sc;
    }
}

// ---- conv: MODE 0 = stats pass, MODE 1 = write pass; SRC 0 = bf16, 1 = fp32
template <int MODE, int SRC>
__launch_bounds__(512)
__global__ void k_conv(const short* __restrict__ xb, const float* __restrict__ xf,
                       const void* __restrict__ e2e, const int* __restrict__ flag,
                       const short* __restrict__ wf, float* __restrict__ stats,
                       const float* __restrict__ ss, float* __restrict__ out, int E) {
    __shared__ short lds[40960];   // 80 KB: W fragments; reused as stats scratch
    const int tid = threadIdx.x;
    for (int i = tid; i < 5120; i += 512)
        ((bf16x8*)lds)[i] = ((const bf16x8*)wf)[i];

    const int wave = tid >> 6, lane = tid & 63;
    const int m = lane & 15, q = lane >> 4;
    const int eb = blockIdx.x * 256 + wave * 32;
    const int is64 = *flag;

    // source row ids for the 2 edge groups this lane serves (seg 0 = self)
    int id0[5], id1[5];
    {
        int e0 = eb + m;       int ec0 = (e0 < E) ? e0 : 0;
        int e1 = eb + 16 + m;  int ec1 = (e1 < E) ? e1 : 0;
        id0[0] = ec0; id1[0] = ec1;
        if (is64) {
            const long long* p0 = (const long long*)e2e + (long long)ec0 * 4;
            const long long* p1 = (const long long*)e2e + (long long)ec1 * 4;
            id0[1] = (int)p0[0]; id0[2] = (int)p0[1]; id0[3] = (int)p0[2]; id0[4] = (int)p0[3];
            id1[1] = (int)p1[0]; id1[2] = (int)p1[1]; id1[3] = (int)p1[2]; id1[4] = (int)p1[3];
        } else {
            i32x4 v0 = ((const i32x4*)e2e)[ec0];
            i32x4 v1 = ((const i32x4*)e2e)[ec1];
            id0[1] = v0[0]; id0[2] = v0[1]; id0[3] = v0[2]; id0[4] = v0[3];
            id1[1] = v1[0]; id1[2] = v1[1]; id1[3] = v1[2]; id1[4] = v1[3];
        }
    }

    f32x4 acc0[8], acc1[8];
#pragma unroll
    for (int nt = 0; nt < 8; ++nt) { acc0[nt] = (f32x4)(0.0f); acc1[nt] = (f32x4)(0.0f); }

    __syncthreads();

#pragma unroll
    for (int t = 0; t < 10; ++t) {
        const int s = t >> 1;
        const int off = (t & 1) * 32 + q * 8;   // element offset within 64-ch row
        bf16x8 a0, a1;
        if (SRC == 0) {
            a0 = *(const bf16x8*)(xb + (size_t)id0[s] * 64 + off);
            a1 = *(const bf16x8*)(xb + (size_t)id1[s] * 64 + off);
        } else {
            const f32x4* p0 = (const f32x4*)(xf + (size_t)id0[s] * 64 + off);
            const f32x4* p1 = (const f32x4*)(xf + (size_t)id1[s] * 64 + off);
            f32x4 u0 = p0[0], u1 = p0[1], w0 = p1[0], w1 = p1[1];
#pragma unroll
            for (int j = 0; j < 4; ++j) {
                a0[j] = (short)f2bf(u0[j]); a0[j + 4] = (short)f2bf(u1[j]);
                a1[j] = (short)f2bf(w0[j]); a1[j + 4] = (short)f2bf(w1[j]);
            }
        }
#pragma unroll
        for (int nt = 0; nt < 8; ++nt) {
            bf16x8 b = ((const bf16x8*)lds)[(t * 8 + nt) * 64 + lane];
            acc0[nt] = __builtin_amdgcn_mfma_f32_16x16x32_bf16(a0, b, acc0[nt], 0, 0, 0);
            acc1[nt] = __builtin_amdgcn_mfma_f32_16x16x32_bf16(a1, b, acc1[nt], 0, 0, 0);
        }
    }

    // D layout: col = lane&15 (channel nt*16+m), row = q*4 + r (edge offset)
    if (MODE == 0) {
        float ps[8], pq[8];
#pragma unroll
        for (int nt = 0; nt < 8; ++nt) {
            float a = 0.0f, b = 0.0f;
#pragma unroll
            for (int r = 0; r < 4; ++r) {
                int ea = eb + q * 4 + r;
                float v = (ea < E) ? acc0[nt][r] : 0.0f;
                a += v; b += v * v;
                int e2 = eb + 16 + q * 4 + r;
                float w = (e2 < E) ? acc1[nt][r] : 0.0f;
                a += w; b += w * w;
            }
            a += __shfl_xor(a, 16); a += __shfl_xor(a, 32);
            b += __shfl_xor(b, 16); b += __shfl_xor(b, 32);
            ps[nt] = a; pq[nt] = b;
        }
        __syncthreads();   // everyone done reading Wf before scratch reuse
        if (q == 0) {
            float* lf = (float*)lds;
#pragma unroll
            for (int nt = 0; nt < 8; ++nt) {
                lf[wave * 256 + nt * 16 + m]       = ps[nt];
                lf[wave * 256 + 128 + nt * 16 + m] = pq[nt];
            }
        }
        __syncthreads();
        if (tid < 256) {
            const float* lf = (const float*)lds;
            float v = 0.0f;
#pragma unroll
            for (int w = 0; w < 8; ++w) v += lf[w * 256 + tid];
            atomicAdd(&stats[tid], v);
        }
    } else {
#pragma unroll
        for (int nt = 0; nt < 8; ++nt) {
            const int c = nt * 16 + m;
            const float sc = ss[c], sh = ss[128 + c];
#pragma unroll
            for (int r = 0; r < 4; ++r) {
                int ea = eb + q * 4 + r;
                if (ea < E) out[(size_t)ea * 128 + c] = fmaxf(acc0[nt][r] * sc + sh, 0.0f);
                int e2 = eb + 16 + q * 4 + r;
                if (e2 < E) out[(size_t)e2 * 128 + c] = fmaxf(acc1[nt][r] * sc + sh, 0.0f);
            }
        }
    }
}

extern "C" void kernel_launch(void* const* d_in, const int* in_sizes, int n_in,
                              void* d_out, int out_size, void* d_ws, size_t ws_size,
                              hipStream_t stream) {
    const float* x     = (const float*)d_in[0];
    const void*  e2e   = d_in[1];
    const float* W     = (const float*)d_in[2];
    // d_in[3] = b : cancels exactly in BatchNorm -> unused
    const float* gamma = (const float*)d_in[4];
    const float* beta  = (const float*)d_in[5];
    float* out = (float*)d_out;
    const int E = in_sizes[0] / 64;

    char* ws = (char*)d_ws;
    const size_t xbBytes = (size_t)E * 64 * 2;
    const size_t need = xbBytes + 81920 + 4096;
    const bool bf = (ws_size >= need);
    const size_t wfOff    = bf ? xbBytes : 0;
    const size_t statsOff = wfOff + 81920;
    const size_t ssOff    = statsOff + 1024;
    const size_t flagOff  = ssOff + 1024;

    short* xb    = (short*)ws;
    short* wf    = (short*)(ws + wfOff);
    float* stats = (float*)(ws + statsOff);
    float* ss    = (float*)(ws + ssOff);
    int*   flag  = (int*)(ws + flagOff);

    k_prep<<<1, 256, 0, stream>>>((const int*)e2e, stats, flag);
    k_wpack<<<10, 512, 0, stream>>>(W, wf);
    const int nb = (E + 255) / 256;
    if (bf) {
        k_convert<<<2048, 256, 0, stream>>>(x, xb, E * 8);
        k_conv<0, 0><<<nb, 512, 0, stream>>>(xb, x, e2e, flag, wf, stats, ss, out, E);
        k_finalize<<<1, 128, 0, stream>>>(stats, gamma, beta, ss, E);
        k_conv<1, 0><<<nb, 512, 0, stream>>>(xb, x, e2e, flag, wf, stats, ss, out, E);
    } else {
        k_conv<0, 1><<<nb, 512, 0, stream>>>(xb, x, e2e, flag, wf, stats, ss, out, E);
        k_finalize<<<1, 128, 0, stream>>>(stats, gamma, beta, ss, E);
        k_conv<1, 1><<<nb, 512, 0, stream>>>(xb, x, e2e, flag, wf, stats, ss, out, E);
    }
}

// Round 2
// 477.708 us; speedup vs baseline: 1.0817x; 1.0817x over previous
//
#include <hip/hip_runtime.h>
#include <hip/hip_bf16.h>

// MeshConv: gather(self+4 neighbors) -> conv1d(k=5) -> BatchNorm(train) -> ReLU
//  - bias b cancels in BN -> ignored
//  - x,W cast to bf16 -> MFMA 16x16x32; xb (128MB) kept L3-resident (nt hints on streams)
//  - pass1: conv + stats, stores conv result bf16 (cb, 256MB) via LDS transpose
//  - pass2: streaming normalize: read cb, scale/shift+relu, write fp32 out
//  - fallback to recompute scheme if ws too small for cb

typedef short bf16x8 __attribute__((ext_vector_type(8)));
typedef float f32x4  __attribute__((ext_vector_type(4)));
typedef int   i32x4  __attribute__((ext_vector_type(4)));

__device__ __forceinline__ unsigned short f2bf(float f) {
    unsigned u = __float_as_uint(f);
    u += 0x7fffu + ((u >> 16) & 1u);   // RNE
    return (unsigned short)(u >> 16);
}
__device__ __forceinline__ float bf2f(unsigned short s) {
    return __uint_as_float(((unsigned)s) << 16);
}

// ---- prep: zero stats, detect e2e element width ----------------------------
__global__ void k_prep(const int* __restrict__ e2e, float* __restrict__ stats,
                       int* __restrict__ flag) {
    __shared__ int sOr;
    if (threadIdx.x == 0) sOr = 0;
    __syncthreads();
    int o = 0;
    for (int j = threadIdx.x; j < 1024; j += blockDim.x)
        o |= e2e[2 * j + 1];           // high words if int64, random ids if int32
    if (o) atomicOr(&sOr, 1);
    if (threadIdx.x < 256) stats[threadIdx.x] = 0.0f;
    __syncthreads();
    if (threadIdx.x == 0) *flag = (sOr == 0) ? 1 : 0;   // 1 => int64
}

// ---- pack W[o][c][k5] into B-fragment order, bf16 --------------------------
__global__ void k_wpack(const float* __restrict__ W, short* __restrict__ wf) {
    int g = blockIdx.x * blockDim.x + threadIdx.x;
    if (g >= 5120) return;
    int lane = g & 63, nt = (g >> 6) & 7, t = g >> 9;
    int o  = nt * 16 + (lane & 15);
    int c0 = (t & 1) * 32 + (lane >> 4) * 8;
    int k5 = t >> 1;
    bf16x8 v;
#pragma unroll
    for (int j = 0; j < 8; ++j)
        v[j] = (short)f2bf(W[(o * 64 + c0 + j) * 5 + k5]);
    ((bf16x8*)wf)[g] = v;
}

// ---- x fp32 -> bf16 (x loads nontemporal: single-use, keep L3 for xb) ------
__global__ void k_convert(const float* __restrict__ x, short* __restrict__ xb, int n8) {
    int i = blockIdx.x * blockDim.x + threadIdx.x;
    int stride = gridDim.x * blockDim.x;
    for (; i < n8; i += stride) {
        const f32x4* p = (const f32x4*)(x + (size_t)i * 8);
        f32x4 a = __builtin_nontemporal_load(p);
        f32x4 b = __builtin_nontemporal_load(p + 1);
        bf16x8 o;
        o[0] = (short)f2bf(a[0]); o[1] = (short)f2bf(a[1]);
        o[2] = (short)f2bf(a[2]); o[3] = (short)f2bf(a[3]);
        o[4] = (short)f2bf(b[0]); o[5] = (short)f2bf(b[1]);
        o[6] = (short)f2bf(b[2]); o[7] = (short)f2bf(b[3]);
        ((bf16x8*)xb)[i] = o;
    }
}

// ---- finalize: scale/shift from stats --------------------------------------
__global__ void k_finalize(const float* __restrict__ stats, const float* __restrict__ gamma,
                           const float* __restrict__ beta, float* __restrict__ ss, int E) {
    int c = threadIdx.x;
    if (c < 128) {
        float inv = 1.0f / (float)E;
        float mu  = stats[c] * inv;
        float var = stats[128 + c] * inv - mu * mu;
        float sc  = gamma[c] * rsqrtf(var + 1e-5f);
        ss[c]       = sc;
        ss[128 + c] = beta[c] - mu * sc;
    }
}

// ---- streaming normalize: cb(bf16) -> out(fp32), relu ----------------------
__global__ void k_norm(const short* __restrict__ cb, const float* __restrict__ ss,
                       float* __restrict__ out, int n8) {
    __shared__ float sss[256];
    if (threadIdx.x < 256) sss[threadIdx.x] = ss[threadIdx.x];
    __syncthreads();
    int i = blockIdx.x * blockDim.x + threadIdx.x;
    int stride = gridDim.x * blockDim.x;
    for (; i < n8; i += stride) {
        bf16x8 v = __builtin_nontemporal_load((const bf16x8*)(cb + (size_t)i * 8));
        int c0 = (i & 15) * 8;
        f32x4 sa = *(const f32x4*)(sss + c0);
        f32x4 sb = *(const f32x4*)(sss + c0 + 4);
        f32x4 ha = *(const f32x4*)(sss + 128 + c0);
        f32x4 hb = *(const f32x4*)(sss + 128 + c0 + 4);
        f32x4 o0, o1;
#pragma unroll
        for (int j = 0; j < 4; ++j) {
            o0[j] = fmaxf(bf2f((unsigned short)v[j])     * sa[j] + ha[j], 0.0f);
            o1[j] = fmaxf(bf2f((unsigned short)v[j + 4]) * sb[j] + hb[j], 0.0f);
        }
        f32x4* po = (f32x4*)(out + (size_t)i * 8);
        __builtin_nontemporal_store(o0, po);
        __builtin_nontemporal_store(o1, po + 1);
    }
}

// ---- conv: MODE 0 = stats pass (CB=1: also store conv bf16), MODE 1 = recompute+write
template <int MODE, int SRC, int CB>
__launch_bounds__(512)
__global__ void k_conv(const short* __restrict__ xb, const float* __restrict__ xf,
                       const void* __restrict__ e2e, const int* __restrict__ flag,
                       const short* __restrict__ wf, float* __restrict__ stats,
                       const float* __restrict__ ss, short* __restrict__ cb,
                       float* __restrict__ out, int E) {
    __shared__ short lds[40960];   // 80 KB: W fragments; reused as scratch after sync
    const int tid = threadIdx.x;
    for (int i = tid; i < 5120; i += 512)
        ((bf16x8*)lds)[i] = ((const bf16x8*)wf)[i];

    const int wave = tid >> 6, lane = tid & 63;
    const int m = lane & 15, q = lane >> 4;
    const int eb = blockIdx.x * 256 + wave * 32;
    const int is64 = *flag;

    int id0[5], id1[5];
    {
        int e0 = eb + m;       int ec0 = (e0 < E) ? e0 : 0;
        int e1 = eb + 16 + m;  int ec1 = (e1 < E) ? e1 : 0;
        id0[0] = ec0; id1[0] = ec1;
        if (is64) {
            const long long* p0 = (const long long*)e2e + (long long)ec0 * 4;
            const long long* p1 = (const long long*)e2e + (long long)ec1 * 4;
            id0[1] = (int)p0[0]; id0[2] = (int)p0[1]; id0[3] = (int)p0[2]; id0[4] = (int)p0[3];
            id1[1] = (int)p1[0]; id1[2] = (int)p1[1]; id1[3] = (int)p1[2]; id1[4] = (int)p1[3];
        } else {
            i32x4 v0 = ((const i32x4*)e2e)[ec0];
            i32x4 v1 = ((const i32x4*)e2e)[ec1];
            id0[1] = v0[0]; id0[2] = v0[1]; id0[3] = v0[2]; id0[4] = v0[3];
            id1[1] = v1[0]; id1[2] = v1[1]; id1[3] = v1[2]; id1[4] = v1[3];
        }
    }

    f32x4 acc0[8], acc1[8];
#pragma unroll
    for (int nt = 0; nt < 8; ++nt) { acc0[nt] = (f32x4)(0.0f); acc1[nt] = (f32x4)(0.0f); }

    __syncthreads();

#pragma unroll
    for (int t = 0; t < 10; ++t) {
        const int s = t >> 1;
        const int off = (t & 1) * 32 + q * 8;
        bf16x8 a0, a1;
        if (SRC == 0) {
            a0 = *(const bf16x8*)(xb + (size_t)id0[s] * 64 + off);
            a1 = *(const bf16x8*)(xb + (size_t)id1[s] * 64 + off);
        } else {
            const f32x4* p0 = (const f32x4*)(xf + (size_t)id0[s] * 64 + off);
            const f32x4* p1 = (const f32x4*)(xf + (size_t)id1[s] * 64 + off);
            f32x4 u0 = p0[0], u1 = p0[1], w0 = p1[0], w1 = p1[1];
#pragma unroll
            for (int j = 0; j < 4; ++j) {
                a0[j] = (short)f2bf(u0[j]); a0[j + 4] = (short)f2bf(u1[j]);
                a1[j] = (short)f2bf(w0[j]); a1[j + 4] = (short)f2bf(w1[j]);
            }
        }
#pragma unroll
        for (int nt = 0; nt < 8; ++nt) {
            bf16x8 b = ((const bf16x8*)lds)[(t * 8 + nt) * 64 + lane];
            acc0[nt] = __builtin_amdgcn_mfma_f32_16x16x32_bf16(a0, b, acc0[nt], 0, 0, 0);
            acc1[nt] = __builtin_amdgcn_mfma_f32_16x16x32_bf16(a1, b, acc1[nt], 0, 0, 0);
        }
    }

    // D layout: col = lane&15 (channel nt*16+m), row = q*4 + r (edge offset)
    if (MODE == 0) {
        float ps[8], pq[8];
#pragma unroll
        for (int nt = 0; nt < 8; ++nt) {
            float a = 0.0f, b = 0.0f;
#pragma unroll
            for (int r = 0; r < 4; ++r) {
                int ea = eb + q * 4 + r;
                float v = (ea < E) ? acc0[nt][r] : 0.0f;
                a += v; b += v * v;
                int e2 = eb + 16 + q * 4 + r;
                float w = (e2 < E) ? acc1[nt][r] : 0.0f;
                a += w; b += w * w;
            }
            a += __shfl_xor(a, 16); a += __shfl_xor(a, 32);
            b += __shfl_xor(b, 16); b += __shfl_xor(b, 32);
            ps[nt] = a; pq[nt] = b;
        }
        __syncthreads();   // all waves done reading Wf -> LDS reusable

        if (CB) {
            // per-wave transpose scratch: 32 rows x 132 shorts (stride 132 kills
            // bank conflicts: bank = (8q + 8nt + m/2 + 2r) mod 32 covers all banks)
            short* sw = lds + wave * 4224;
#pragma unroll
            for (int nt = 0; nt < 8; ++nt) {
                const int cch = nt * 16 + m;
#pragma unroll
                for (int r = 0; r < 4; ++r) {
                    sw[(q * 4 + r) * 132 + cch]        = (short)f2bf(acc0[nt][r]);
                    sw[(16 + q * 4 + r) * 132 + cch]   = (short)f2bf(acc1[nt][r]);
                }
            }
            // readback + coalesced nontemporal store: per instr 4 rows x 256 B = 1 KB
#pragma unroll
            for (int it = 0; it < 8; ++it) {
                int row  = it * 4 + (lane >> 4);
                int col8 = lane & 15;
                int edge = eb + row;
                bf16x8 v = *(const bf16x8*)(sw + row * 132 + col8 * 8);
                if (edge < E)
                    __builtin_nontemporal_store(
                        v, (bf16x8*)(cb + (size_t)edge * 128 + col8 * 8));
            }
            __syncthreads();
        }

        {
            float* lf = (float*)lds;
            if (q == 0) {
#pragma unroll
                for (int nt = 0; nt < 8; ++nt) {
                    lf[wave * 256 + nt * 16 + m]       = ps[nt];
                    lf[wave * 256 + 128 + nt * 16 + m] = pq[nt];
                }
            }
            __syncthreads();
            if (tid < 256) {
                float v = 0.0f;
#pragma unroll
                for (int w = 0; w < 8; ++w) v += lf[w * 256 + tid];
                atomicAdd(&stats[tid], v);
            }
        }
    } else {
#pragma unroll
        for (int nt = 0; nt < 8; ++nt) {
            const int c = nt * 16 + m;
            const float sc = ss[c], sh = ss[128 + c];
#pragma unroll
            for (int r = 0; r < 4; ++r) {
                int ea = eb + q * 4 + r;
                if (ea < E) out[(size_t)ea * 128 + c] = fmaxf(acc0[nt][r] * sc + sh, 0.0f);
                int e2 = eb + 16 + q * 4 + r;
                if (e2 < E) out[(size_t)e2 * 128 + c] = fmaxf(acc1[nt][r] * sc + sh, 0.0f);
            }
        }
    }
}

extern "C" void kernel_launch(void* const* d_in, const int* in_sizes, int n_in,
                              void* d_out, int out_size, void* d_ws, size_t ws_size,
                              hipStream_t stream) {
    const float* x     = (const float*)d_in[0];
    const void*  e2e   = d_in[1];
    const float* W     = (const float*)d_in[2];
    // d_in[3] = b : cancels exactly in BatchNorm -> unused
    const float* gamma = (const float*)d_in[4];
    const float* beta  = (const float*)d_in[5];
    float* out = (float*)d_out;
    const int E = in_sizes[0] / 64;

    char* ws = (char*)d_ws;
    const size_t xbBytes = (size_t)E * 128;        // bf16 x
    const size_t cbBytes = (size_t)E * 256;        // bf16 conv result
    const size_t tailBytes = 81920 + 4096;
    const bool bf   = (ws_size >= xbBytes + tailBytes);
    const bool cbok = (ws_size >= xbBytes + cbBytes + tailBytes);

    size_t off = 0;
    short* xbp = (short*)ws;              if (bf)   off += xbBytes;
    short* cbp = (short*)(ws + off);      if (cbok) off += cbBytes;
    short* wfp = (short*)(ws + off);      off += 81920;
    float* stats = (float*)(ws + off);    off += 1024;
    float* ssp   = (float*)(ws + off);    off += 1024;
    int*   flag  = (int*)(ws + off);

    k_prep<<<1, 256, 0, stream>>>((const int*)e2e, stats, flag);
    k_wpack<<<10, 512, 0, stream>>>(W, wfp);
    const int nb = (E + 255) / 256;
    if (cbok) {
        k_convert<<<2048, 256, 0, stream>>>(x, xbp, E * 8);
        k_conv<0, 0, 1><<<nb, 512, 0, stream>>>(xbp, x, e2e, flag, wfp, stats, ssp, cbp, out, E);
        k_finalize<<<1, 128, 0, stream>>>(stats, gamma, beta, ssp, E);
        k_norm<<<4096, 256, 0, stream>>>(cbp, ssp, out, E * 16);
    } else if (bf) {
        k_convert<<<2048, 256, 0, stream>>>(x, xbp, E * 8);
        k_conv<0, 0, 0><<<nb, 512, 0, stream>>>(xbp, x, e2e, flag, wfp, stats, ssp, cbp, out, E);
        k_finalize<<<1, 128, 0, stream>>>(stats, gamma, beta, ssp, E);
        k_conv<1, 0, 0><<<nb, 512, 0, stream>>>(xbp, x, e2e, flag, wfp, stats, ssp, cbp, out, E);
    } else {
        k_conv<0, 1, 0><<<nb, 512, 0, stream>>>(xbp, x, e2e, flag, wfp, stats, ssp, cbp, out, E);
        k_finalize<<<1, 128, 0, stream>>>(stats, gamma, beta, ssp, E);
        k_conv<1, 1, 0><<<nb, 512, 0, stream>>>(xbp, x, e2e, flag, wfp, stats, ssp, cbp, out, E);
    }
}

// Round 3
// 448.542 us; speedup vs baseline: 1.1520x; 1.0650x over previous
//
#include <hip/hip_runtime.h>
#include <hip/hip_bf16.h>

// MeshConv: gather(self+4 neighbors) -> conv1d(k=5) -> BatchNorm(train) -> ReLU
//  - bias b cancels in BN -> ignored
//  - x,W cast to bf16 -> MFMA 16x16x32; xb (128MB) kept L3-resident (nt hints on streams)
//  - pass1: conv + stats, stores conv result bf16 (cb, 256MB) via LDS transpose
//  - pass2: streaming normalize: read cb, scale/shift+relu, write fp32 out
//  - conv pass: explicit 2-deep gather pipeline, VGPR capped for 16 waves/CU

typedef short bf16x8 __attribute__((ext_vector_type(8)));
typedef float f32x4  __attribute__((ext_vector_type(4)));
typedef int   i32x4  __attribute__((ext_vector_type(4)));

__device__ __forceinline__ unsigned short f2bf(float f) {
    unsigned u = __float_as_uint(f);
    u += 0x7fffu + ((u >> 16) & 1u);   // RNE
    return (unsigned short)(u >> 16);
}
__device__ __forceinline__ float bf2f(unsigned short s) {
    return __uint_as_float(((unsigned)s) << 16);
}

// ---- setup: pack W into B-fragment order (bf16) + zero stats + e2e width detect
__global__ void k_setup(const float* __restrict__ W, short* __restrict__ wf,
                        const int* __restrict__ e2e, float* __restrict__ stats,
                        int* __restrict__ flag) {
    int tid = threadIdx.x;
    int g = blockIdx.x * blockDim.x + tid;
    if (g < 5120) {
        int lane = g & 63, nt = (g >> 6) & 7, t = g >> 9;
        int o  = nt * 16 + (lane & 15);
        int c0 = (t & 1) * 32 + (lane >> 4) * 8;
        int k5 = t >> 1;
        bf16x8 v;
#pragma unroll
        for (int j = 0; j < 8; ++j)
            v[j] = (short)f2bf(W[(o * 64 + c0 + j) * 5 + k5]);
        ((bf16x8*)wf)[g] = v;
    }
    if (blockIdx.x == 0) {
        __shared__ int sOr;
        if (tid == 0) sOr = 0;
        __syncthreads();
        int o = 0;
        for (int j = tid; j < 1024; j += blockDim.x)
            o |= e2e[2 * j + 1];       // high words if int64, random ids if int32
        if (o) atomicOr(&sOr, 1);
        if (tid < 256) stats[tid] = 0.0f;
        __syncthreads();
        if (tid == 0) *flag = (sOr == 0) ? 1 : 0;   // 1 => int64
    }
}

// ---- x fp32 -> bf16 (x loads nontemporal: single-use, keep L3 for xb) ------
__global__ void k_convert(const float* __restrict__ x, short* __restrict__ xb, int n8) {
    int i = blockIdx.x * blockDim.x + threadIdx.x;
    int stride = gridDim.x * blockDim.x;
    for (; i < n8; i += stride) {
        const f32x4* p = (const f32x4*)(x + (size_t)i * 8);
        f32x4 a = __builtin_nontemporal_load(p);
        f32x4 b = __builtin_nontemporal_load(p + 1);
        bf16x8 o;
        o[0] = (short)f2bf(a[0]); o[1] = (short)f2bf(a[1]);
        o[2] = (short)f2bf(a[2]); o[3] = (short)f2bf(a[3]);
        o[4] = (short)f2bf(b[0]); o[5] = (short)f2bf(b[1]);
        o[6] = (short)f2bf(b[2]); o[7] = (short)f2bf(b[3]);
        ((bf16x8*)xb)[i] = o;      // normal store: xb must land in L3
    }
}

// ---- finalize: scale/shift from stats --------------------------------------
__global__ void k_finalize(const float* __restrict__ stats, const float* __restrict__ gamma,
                           const float* __restrict__ beta, float* __restrict__ ss, int E) {
    int c = threadIdx.x;
    if (c < 128) {
        float inv = 1.0f / (float)E;
        float mu  = stats[c] * inv;
        float var = stats[128 + c] * inv - mu * mu;
        float sc  = gamma[c] * rsqrtf(var + 1e-5f);
        ss[c]       = sc;
        ss[128 + c] = beta[c] - mu * sc;
    }
}

// ---- streaming normalize: cb(bf16) -> out(fp32), relu ----------------------
__global__ void k_norm(const short* __restrict__ cb, const float* __restrict__ ss,
                       float* __restrict__ out, int n8) {
    __shared__ float sss[256];
    if (threadIdx.x < 256) sss[threadIdx.x] = ss[threadIdx.x];
    __syncthreads();
    int i = blockIdx.x * blockDim.x + threadIdx.x;
    int stride = gridDim.x * blockDim.x;
    for (; i < n8; i += stride) {
        bf16x8 v = __builtin_nontemporal_load((const bf16x8*)(cb + (size_t)i * 8));
        int c0 = (i & 15) * 8;
        f32x4 sa = *(const f32x4*)(sss + c0);
        f32x4 sb = *(const f32x4*)(sss + c0 + 4);
        f32x4 ha = *(const f32x4*)(sss + 128 + c0);
        f32x4 hb = *(const f32x4*)(sss + 128 + c0 + 4);
        f32x4 o0, o1;
#pragma unroll
        for (int j = 0; j < 4; ++j) {
            o0[j] = fmaxf(bf2f((unsigned short)v[j])     * sa[j] + ha[j], 0.0f);
            o1[j] = fmaxf(bf2f((unsigned short)v[j + 4]) * sb[j] + hb[j], 0.0f);
        }
        f32x4* po = (f32x4*)(out + (size_t)i * 8);
        __builtin_nontemporal_store(o0, po);
        __builtin_nontemporal_store(o1, po + 1);
    }
}

// ---- conv: MODE 0 = stats pass (CB=1: also store conv bf16), MODE 1 = recompute+write
template <int MODE, int SRC, int CB>
__launch_bounds__(512, 4)
__global__ void k_conv(const short* __restrict__ xb, const float* __restrict__ xf,
                       const void* __restrict__ e2e, const int* __restrict__ flag,
                       const short* __restrict__ wf, float* __restrict__ stats,
                       const float* __restrict__ ss, short* __restrict__ cb,
                       float* __restrict__ out, int E) {
    __shared__ short lds[40960];   // 80 KB: W fragments; reused as scratch after sync
    const int tid = threadIdx.x;
    const int wave = tid >> 6, lane = tid & 63;
    const int m = lane & 15, q = lane >> 4;
    const int eb = blockIdx.x * 256 + wave * 32;

    // ---- ids first: e2e load latency hides under W staging ----
    const int is64 = *flag;
    int id0[5], id1[5];
    {
        int e0 = eb + m;       int ec0 = (e0 < E) ? e0 : 0;
        int e1 = eb + 16 + m;  int ec1 = (e1 < E) ? e1 : 0;
        id0[0] = ec0; id1[0] = ec1;
        const i32x4* p = (const i32x4*)e2e;
        if (is64) {
            i32x4 a0 = __builtin_nontemporal_load(p + 2 * ec0);
            i32x4 a1 = __builtin_nontemporal_load(p + 2 * ec0 + 1);
            i32x4 b0 = __builtin_nontemporal_load(p + 2 * ec1);
            i32x4 b1 = __builtin_nontemporal_load(p + 2 * ec1 + 1);
            id0[1] = a0[0]; id0[2] = a0[2]; id0[3] = a1[0]; id0[4] = a1[2];
            id1[1] = b0[0]; id1[2] = b0[2]; id1[3] = b1[0]; id1[4] = b1[2];
        } else {
            i32x4 v0 = __builtin_nontemporal_load(p + ec0);
            i32x4 v1 = __builtin_nontemporal_load(p + ec1);
            id0[1] = v0[0]; id0[2] = v0[1]; id0[3] = v0[2]; id0[4] = v0[3];
            id1[1] = v1[0]; id1[2] = v1[1]; id1[3] = v1[2]; id1[4] = v1[3];
        }
    }

    // ---- stage W fragments into LDS ----
    for (int i = tid; i < 5120; i += 512)
        ((bf16x8*)lds)[i] = ((const bf16x8*)wf)[i];

    f32x4 acc0[8], acc1[8];
#pragma unroll
    for (int nt = 0; nt < 8; ++nt) { acc0[nt] = (f32x4)(0.0f); acc1[nt] = (f32x4)(0.0f); }

    if constexpr (SRC == 0) {
        // prefetch t=0 A-fragments (completes during staging/barrier)
        bf16x8 a0c = *(const bf16x8*)(xb + (size_t)id0[0] * 64 + q * 8);
        bf16x8 a1c = *(const bf16x8*)(xb + (size_t)id1[0] * 64 + q * 8);
        bf16x8 a0n = a0c, a1n = a1c;
        __syncthreads();
#pragma unroll
        for (int t = 0; t < 10; ++t) {
            if (t < 9) {   // issue next-stage gathers before this stage's MFMAs
                const int s = (t + 1) >> 1;
                const int off = ((t + 1) & 1) * 32 + q * 8;
                a0n = *(const bf16x8*)(xb + (size_t)id0[s] * 64 + off);
                a1n = *(const bf16x8*)(xb + (size_t)id1[s] * 64 + off);
            }
#pragma unroll
            for (int nt = 0; nt < 8; ++nt) {
                bf16x8 b = ((const bf16x8*)lds)[(t * 8 + nt) * 64 + lane];
                acc0[nt] = __builtin_amdgcn_mfma_f32_16x16x32_bf16(a0c, b, acc0[nt], 0, 0, 0);
                acc1[nt] = __builtin_amdgcn_mfma_f32_16x16x32_bf16(a1c, b, acc1[nt], 0, 0, 0);
            }
            a0c = a0n; a1c = a1n;
        }
    } else {
        __syncthreads();
#pragma unroll
        for (int t = 0; t < 10; ++t) {
            const int s = t >> 1;
            const int off = (t & 1) * 32 + q * 8;
            bf16x8 a0, a1;
            const f32x4* p0 = (const f32x4*)(xf + (size_t)id0[s] * 64 + off);
            const f32x4* p1 = (const f32x4*)(xf + (size_t)id1[s] * 64 + off);
            f32x4 u0 = p0[0], u1 = p0[1], w0 = p1[0], w1 = p1[1];
#pragma unroll
            for (int j = 0; j < 4; ++j) {
                a0[j] = (short)f2bf(u0[j]); a0[j + 4] = (short)f2bf(u1[j]);
                a1[j] = (short)f2bf(w0[j]); a1[j + 4] = (short)f2bf(w1[j]);
            }
#pragma unroll
            for (int nt = 0; nt < 8; ++nt) {
                bf16x8 b = ((const bf16x8*)lds)[(t * 8 + nt) * 64 + lane];
                acc0[nt] = __builtin_amdgcn_mfma_f32_16x16x32_bf16(a0, b, acc0[nt], 0, 0, 0);
                acc1[nt] = __builtin_amdgcn_mfma_f32_16x16x32_bf16(a1, b, acc1[nt], 0, 0, 0);
            }
        }
    }

    // D layout: col = lane&15 (channel nt*16+m), row = q*4 + r (edge offset)
    if (MODE == 0) {
        float ps[8], pq[8];
#pragma unroll
        for (int nt = 0; nt < 8; ++nt) {
            float a = 0.0f, b = 0.0f;
#pragma unroll
            for (int r = 0; r < 4; ++r) {
                int ea = eb + q * 4 + r;
                float v = (ea < E) ? acc0[nt][r] : 0.0f;
                a += v; b += v * v;
                int e2 = eb + 16 + q * 4 + r;
                float w = (e2 < E) ? acc1[nt][r] : 0.0f;
                a += w; b += w * w;
            }
            a += __shfl_xor(a, 16); a += __shfl_xor(a, 32);
            b += __shfl_xor(b, 16); b += __shfl_xor(b, 32);
            ps[nt] = a; pq[nt] = b;
        }
        __syncthreads();   // all waves done reading Wf -> LDS reusable

        if (CB) {
            // per-wave transpose scratch: 32 rows x 132 shorts (stride breaks
            // power-of-2 bank collisions)
            short* sw = lds + wave * 4224;
#pragma unroll
            for (int nt = 0; nt < 8; ++nt) {
                const int cch = nt * 16 + m;
#pragma unroll
                for (int r = 0; r < 4; ++r) {
                    sw[(q * 4 + r) * 132 + cch]        = (short)f2bf(acc0[nt][r]);
                    sw[(16 + q * 4 + r) * 132 + cch]   = (short)f2bf(acc1[nt][r]);
                }
            }
            // readback + coalesced nontemporal store: per instr 4 rows x 256 B = 1 KB
#pragma unroll
            for (int it = 0; it < 8; ++it) {
                int row  = it * 4 + (lane >> 4);
                int col8 = lane & 15;
                int edge = eb + row;
                bf16x8 v = *(const bf16x8*)(sw + row * 132 + col8 * 8);
                if (edge < E)
                    __builtin_nontemporal_store(
                        v, (bf16x8*)(cb + (size_t)edge * 128 + col8 * 8));
            }
            __syncthreads();
        }

        {
            float* lf = (float*)lds;
            if (q == 0) {
#pragma unroll
                for (int nt = 0; nt < 8; ++nt) {
                    lf[wave * 256 + nt * 16 + m]       = ps[nt];
                    lf[wave * 256 + 128 + nt * 16 + m] = pq[nt];
                }
            }
            __syncthreads();
            if (tid < 256) {
                float v = 0.0f;
#pragma unroll
                for (int w = 0; w < 8; ++w) v += lf[w * 256 + tid];
                atomicAdd(&stats[tid], v);
            }
        }
    } else {
#pragma unroll
        for (int nt = 0; nt < 8; ++nt) {
            const int c = nt * 16 + m;
            const float sc = ss[c], sh = ss[128 + c];
#pragma unroll
            for (int r = 0; r < 4; ++r) {
                int ea = eb + q * 4 + r;
                if (ea < E) out[(size_t)ea * 128 + c] = fmaxf(acc0[nt][r] * sc + sh, 0.0f);
                int e2 = eb + 16 + q * 4 + r;
                if (e2 < E) out[(size_t)e2 * 128 + c] = fmaxf(acc1[nt][r] * sc + sh, 0.0f);
            }
        }
    }
}

extern "C" void kernel_launch(void* const* d_in, const int* in_sizes, int n_in,
                              void* d_out, int out_size, void* d_ws, size_t ws_size,
                              hipStream_t stream) {
    const float* x     = (const float*)d_in[0];
    const void*  e2e   = d_in[1];
    const float* W     = (const float*)d_in[2];
    // d_in[3] = b : cancels exactly in BatchNorm -> unused
    const float* gamma = (const float*)d_in[4];
    const float* beta  = (const float*)d_in[5];
    float* out = (float*)d_out;
    const int E = in_sizes[0] / 64;

    char* ws = (char*)d_ws;
    const size_t xbBytes = (size_t)E * 128;        // bf16 x
    const size_t cbBytes = (size_t)E * 256;        // bf16 conv result
    const size_t tailBytes = 81920 + 4096;
    const bool bf   = (ws_size >= xbBytes + tailBytes);
    const bool cbok = (ws_size >= xbBytes + cbBytes + tailBytes);

    size_t off = 0;
    short* xbp = (short*)ws;              if (bf)   off += xbBytes;
    short* cbp = (short*)(ws + off);      if (cbok) off += cbBytes;
    short* wfp = (short*)(ws + off);      off += 81920;
    float* stats = (float*)(ws + off);    off += 1024;
    float* ssp   = (float*)(ws + off);    off += 1024;
    int*   flag  = (int*)(ws + off);

    k_setup<<<10, 512, 0, stream>>>(W, wfp, (const int*)e2e, stats, flag);
    const int nb = (E + 255) / 256;
    if (cbok) {
        k_convert<<<2048, 256, 0, stream>>>(x, xbp, E * 8);
        k_conv<0, 0, 1><<<nb, 512, 0, stream>>>(xbp, x, e2e, flag, wfp, stats, ssp, cbp, out, E);
        k_finalize<<<1, 128, 0, stream>>>(stats, gamma, beta, ssp, E);
        k_norm<<<2048, 512, 0, stream>>>(cbp, ssp, out, E * 16);
    } else if (bf) {
        k_convert<<<2048, 256, 0, stream>>>(x, xbp, E * 8);
        k_conv<0, 0, 0><<<nb, 512, 0, stream>>>(xbp, x, e2e, flag, wfp, stats, ssp, cbp, out, E);
        k_finalize<<<1, 128, 0, stream>>>(stats, gamma, beta, ssp, E);
        k_conv<1, 0, 0><<<nb, 512, 0, stream>>>(xbp, x, e2e, flag, wfp, stats, ssp, cbp, out, E);
    } else {
        k_conv<0, 1, 0><<<nb, 512, 0, stream>>>(xbp, x, e2e, flag, wfp, stats, ssp, cbp, out, E);
        k_finalize<<<1, 128, 0, stream>>>(stats, gamma, beta, ssp, E);
        k_conv<1, 1, 0><<<nb, 512, 0, stream>>>(xbp, x, e2e, flag, wfp, stats, ssp, cbp, out, E);
    }
}

// Round 4
// 441.363 us; speedup vs baseline: 1.1708x; 1.0163x over previous
//
#include <hip/hip_runtime.h>
#include <hip/hip_bf16.h>

// MeshConv: gather(self+4 neighbors) -> conv1d(k=5) -> BatchNorm(train) -> ReLU
//  - bias b cancels in BN -> ignored
//  - x,W cast to bf16 -> MFMA 16x16x32; xb (128MB) L3-resident
//  - pass1: conv + stats, stores conv result bf16 (cb) via LDS transpose
//  - pass2: streaming normalize: read cb, scale/shift+relu, write fp32 out
//  - conv K-loop: full-segment prefetch (4 loads in flight = 64 lines/wave)

typedef short bf16x8 __attribute__((ext_vector_type(8)));
typedef float f32x4  __attribute__((ext_vector_type(4)));
typedef int   i32x4  __attribute__((ext_vector_type(4)));

__device__ __forceinline__ unsigned short f2bf(float f) {
    unsigned u = __float_as_uint(f);
    u += 0x7fffu + ((u >> 16) & 1u);   // RNE
    return (unsigned short)(u >> 16);
}
__device__ __forceinline__ float bf2f(unsigned short s) {
    return __uint_as_float(((unsigned)s) << 16);
}

// ---- setup: pack W into B-fragment order (bf16) + zero stats + e2e width detect
__global__ void k_setup(const float* __restrict__ W, short* __restrict__ wf,
                        const int* __restrict__ e2e, float* __restrict__ stats,
                        int* __restrict__ flag) {
    int tid = threadIdx.x;
    int g = blockIdx.x * blockDim.x + tid;
    if (g < 5120) {
        int lane = g & 63, nt = (g >> 6) & 7, t = g >> 9;
        int o  = nt * 16 + (lane & 15);
        int c0 = (t & 1) * 32 + (lane >> 4) * 8;
        int k5 = t >> 1;
        bf16x8 v;
#pragma unroll
        for (int j = 0; j < 8; ++j)
            v[j] = (short)f2bf(W[(o * 64 + c0 + j) * 5 + k5]);
        ((bf16x8*)wf)[g] = v;
    }
    if (blockIdx.x == 0) {
        __shared__ int sOr;
        if (tid == 0) sOr = 0;
        __syncthreads();
        int o = 0;
        for (int j = tid; j < 1024; j += blockDim.x)
            o |= e2e[2 * j + 1];       // high words if int64, random ids if int32
        if (o) atomicOr(&sOr, 1);
        if (tid < 256) stats[tid] = 0.0f;
        __syncthreads();
        if (tid == 0) *flag = (sOr == 0) ? 1 : 0;   // 1 => int64
    }
}

// ---- x fp32 -> bf16 (x loads nontemporal: single-use, keep L3 for xb) ------
__global__ void k_convert(const float* __restrict__ x, short* __restrict__ xb, int n8) {
    int i = blockIdx.x * blockDim.x + threadIdx.x;
    int stride = gridDim.x * blockDim.x;
    for (; i < n8; i += stride) {
        const f32x4* p = (const f32x4*)(x + (size_t)i * 8);
        f32x4 a = __builtin_nontemporal_load(p);
        f32x4 b = __builtin_nontemporal_load(p + 1);
        bf16x8 o;
        o[0] = (short)f2bf(a[0]); o[1] = (short)f2bf(a[1]);
        o[2] = (short)f2bf(a[2]); o[3] = (short)f2bf(a[3]);
        o[4] = (short)f2bf(b[0]); o[5] = (short)f2bf(b[1]);
        o[6] = (short)f2bf(b[2]); o[7] = (short)f2bf(b[3]);
        ((bf16x8*)xb)[i] = o;      // normal store: xb must land in L3
    }
}

// ---- finalize: scale/shift from stats --------------------------------------
__global__ void k_finalize(const float* __restrict__ stats, const float* __restrict__ gamma,
                           const float* __restrict__ beta, float* __restrict__ ss, int E) {
    int c = threadIdx.x;
    if (c < 128) {
        float inv = 1.0f / (float)E;
        float mu  = stats[c] * inv;
        float var = stats[128 + c] * inv - mu * mu;
        float sc  = gamma[c] * rsqrtf(var + 1e-5f);
        ss[c]       = sc;
        ss[128 + c] = beta[c] - mu * sc;
    }
}

// ---- streaming normalize: cb(bf16) -> out(fp32), relu ----------------------
__global__ void k_norm(const short* __restrict__ cb, const float* __restrict__ ss,
                       float* __restrict__ out, int n8) {
    __shared__ float sss[256];
    if (threadIdx.x < 256) sss[threadIdx.x] = ss[threadIdx.x];
    __syncthreads();
    int i = blockIdx.x * blockDim.x + threadIdx.x;
    int stride = gridDim.x * blockDim.x;
    for (; i < n8; i += stride) {
        bf16x8 v = __builtin_nontemporal_load((const bf16x8*)(cb + (size_t)i * 8));
        int c0 = (i & 15) * 8;
        f32x4 sa = *(const f32x4*)(sss + c0);
        f32x4 sb = *(const f32x4*)(sss + c0 + 4);
        f32x4 ha = *(const f32x4*)(sss + 128 + c0);
        f32x4 hb = *(const f32x4*)(sss + 128 + c0 + 4);
        f32x4 o0, o1;
#pragma unroll
        for (int j = 0; j < 4; ++j) {
            o0[j] = fmaxf(bf2f((unsigned short)v[j])     * sa[j] + ha[j], 0.0f);
            o1[j] = fmaxf(bf2f((unsigned short)v[j + 4]) * sb[j] + hb[j], 0.0f);
        }
        f32x4* po = (f32x4*)(out + (size_t)i * 8);
        __builtin_nontemporal_store(o0, po);
        __builtin_nontemporal_store(o1, po + 1);
    }
}

// ---- conv: MODE 0 = stats pass (CB=1: also store conv bf16), MODE 1 = recompute+write
template <int MODE, int SRC, int CB>
__launch_bounds__(512, 4)
__global__ void k_conv(const short* __restrict__ xb, const float* __restrict__ xf,
                       const void* __restrict__ e2e, const int* __restrict__ flag,
                       const short* __restrict__ wf, float* __restrict__ stats,
                       const float* __restrict__ ss, short* __restrict__ cb,
                       float* __restrict__ out, int E) {
    __shared__ short lds[40960];   // 80 KB: W fragments; reused as scratch after sync
    const int tid = threadIdx.x;
    const int wave = tid >> 6, lane = tid & 63;
    const int m = lane & 15, q = lane >> 4;
    const int eb = blockIdx.x * 256 + wave * 32;

    // ---- ids first: e2e load latency hides under W staging ----
    const int is64 = *flag;
    int id0[5], id1[5];
    {
        int e0 = eb + m;       int ec0 = (e0 < E) ? e0 : 0;
        int e1 = eb + 16 + m;  int ec1 = (e1 < E) ? e1 : 0;
        id0[0] = ec0; id1[0] = ec1;
        const i32x4* p = (const i32x4*)e2e;
        if (is64) {
            i32x4 a0 = __builtin_nontemporal_load(p + 2 * ec0);
            i32x4 a1 = __builtin_nontemporal_load(p + 2 * ec0 + 1);
            i32x4 b0 = __builtin_nontemporal_load(p + 2 * ec1);
            i32x4 b1 = __builtin_nontemporal_load(p + 2 * ec1 + 1);
            id0[1] = a0[0]; id0[2] = a0[2]; id0[3] = a1[0]; id0[4] = a1[2];
            id1[1] = b0[0]; id1[2] = b0[2]; id1[3] = b1[0]; id1[4] = b1[2];
        } else {
            i32x4 v0 = __builtin_nontemporal_load(p + ec0);
            i32x4 v1 = __builtin_nontemporal_load(p + ec1);
            id0[1] = v0[0]; id0[2] = v0[1]; id0[3] = v0[2]; id0[4] = v0[3];
            id1[1] = v1[0]; id1[2] = v1[1]; id1[3] = v1[2]; id1[4] = v1[3];
        }
    }

    // ---- stage W fragments into LDS ----
    for (int i = tid; i < 5120; i += 512)
        ((bf16x8*)lds)[i] = ((const bf16x8*)wf)[i];

    f32x4 acc0[8], acc1[8];
#pragma unroll
    for (int nt = 0; nt < 8; ++nt) { acc0[nt] = (f32x4)(0.0f); acc1[nt] = (f32x4)(0.0f); }

    if constexpr (SRC == 0) {
        // full-segment prefetch: seg s = 4 loads (both 64B halves x both row
        // groups); prefetch seg s+1 while the 32 MFMAs of seg s execute.
        const int lo = q * 8, hi = 32 + q * 8;
        bf16x8 c00 = *(const bf16x8*)(xb + (size_t)id0[0] * 64 + lo);
        bf16x8 c01 = *(const bf16x8*)(xb + (size_t)id0[0] * 64 + hi);
        bf16x8 c10 = *(const bf16x8*)(xb + (size_t)id1[0] * 64 + lo);
        bf16x8 c11 = *(const bf16x8*)(xb + (size_t)id1[0] * 64 + hi);
        __syncthreads();
#pragma unroll
        for (int s = 0; s < 5; ++s) {
            bf16x8 n00, n01, n10, n11;
            if (s < 4) {
                n00 = *(const bf16x8*)(xb + (size_t)id0[s + 1] * 64 + lo);
                n01 = *(const bf16x8*)(xb + (size_t)id0[s + 1] * 64 + hi);
                n10 = *(const bf16x8*)(xb + (size_t)id1[s + 1] * 64 + lo);
                n11 = *(const bf16x8*)(xb + (size_t)id1[s + 1] * 64 + hi);
            }
#pragma unroll
            for (int nt = 0; nt < 8; ++nt) {
                bf16x8 b = ((const bf16x8*)lds)[((2 * s) * 8 + nt) * 64 + lane];
                acc0[nt] = __builtin_amdgcn_mfma_f32_16x16x32_bf16(c00, b, acc0[nt], 0, 0, 0);
                acc1[nt] = __builtin_amdgcn_mfma_f32_16x16x32_bf16(c10, b, acc1[nt], 0, 0, 0);
            }
#pragma unroll
            for (int nt = 0; nt < 8; ++nt) {
                bf16x8 b = ((const bf16x8*)lds)[((2 * s + 1) * 8 + nt) * 64 + lane];
                acc0[nt] = __builtin_amdgcn_mfma_f32_16x16x32_bf16(c01, b, acc0[nt], 0, 0, 0);
                acc1[nt] = __builtin_amdgcn_mfma_f32_16x16x32_bf16(c11, b, acc1[nt], 0, 0, 0);
            }
            if (s < 4) { c00 = n00; c01 = n01; c10 = n10; c11 = n11; }
        }
    } else {
        __syncthreads();
#pragma unroll
        for (int t = 0; t < 10; ++t) {
            const int s = t >> 1;
            const int off = (t & 1) * 32 + q * 8;
            bf16x8 a0, a1;
            const f32x4* p0 = (const f32x4*)(xf + (size_t)id0[s] * 64 + off);
            const f32x4* p1 = (const f32x4*)(xf + (size_t)id1[s] * 64 + off);
            f32x4 u0 = p0[0], u1 = p0[1], w0 = p1[0], w1 = p1[1];
#pragma unroll
            for (int j = 0; j < 4; ++j) {
                a0[j] = (short)f2bf(u0[j]); a0[j + 4] = (short)f2bf(u1[j]);
                a1[j] = (short)f2bf(w0[j]); a1[j + 4] = (short)f2bf(w1[j]);
            }
#pragma unroll
            for (int nt = 0; nt < 8; ++nt) {
                bf16x8 b = ((const bf16x8*)lds)[(t * 8 + nt) * 64 + lane];
                acc0[nt] = __builtin_amdgcn_mfma_f32_16x16x32_bf16(a0, b, acc0[nt], 0, 0, 0);
                acc1[nt] = __builtin_amdgcn_mfma_f32_16x16x32_bf16(a1, b, acc1[nt], 0, 0, 0);
            }
        }
    }

    // D layout: col = lane&15 (channel nt*16+m), row = q*4 + r (edge offset)
    if (MODE == 0) {
        float ps[8], pq[8];
#pragma unroll
        for (int nt = 0; nt < 8; ++nt) {
            float a = 0.0f, b = 0.0f;
#pragma unroll
            for (int r = 0; r < 4; ++r) {
                int ea = eb + q * 4 + r;
                float v = (ea < E) ? acc0[nt][r] : 0.0f;
                a += v; b += v * v;
                int e2 = eb + 16 + q * 4 + r;
                float w = (e2 < E) ? acc1[nt][r] : 0.0f;
                a += w; b += w * w;
            }
            a += __shfl_xor(a, 16); a += __shfl_xor(a, 32);
            b += __shfl_xor(b, 16); b += __shfl_xor(b, 32);
            ps[nt] = a; pq[nt] = b;
        }
        __syncthreads();   // all waves done reading Wf -> LDS reusable

        if (CB) {
            // per-wave transpose scratch: 32 rows x 132 shorts (stride breaks
            // power-of-2 bank collisions)
            short* sw = lds + wave * 4224;
#pragma unroll
            for (int nt = 0; nt < 8; ++nt) {
                const int cch = nt * 16 + m;
#pragma unroll
                for (int r = 0; r < 4; ++r) {
                    sw[(q * 4 + r) * 132 + cch]        = (short)f2bf(acc0[nt][r]);
                    sw[(16 + q * 4 + r) * 132 + cch]   = (short)f2bf(acc1[nt][r]);
                }
            }
            // readback + coalesced nontemporal store: per instr 4 rows x 256 B = 1 KB
#pragma unroll
            for (int it = 0; it < 8; ++it) {
                int row  = it * 4 + (lane >> 4);
                int col8 = lane & 15;
                int edge = eb + row;
                bf16x8 v = *(const bf16x8*)(sw + row * 132 + col8 * 8);
                if (edge < E)
                    __builtin_nontemporal_store(
                        v, (bf16x8*)(cb + (size_t)edge * 128 + col8 * 8));
            }
            __syncthreads();
        }

        {
            float* lf = (float*)lds;
            if (q == 0) {
#pragma unroll
                for (int nt = 0; nt < 8; ++nt) {
                    lf[wave * 256 + nt * 16 + m]       = ps[nt];
                    lf[wave * 256 + 128 + nt * 16 + m] = pq[nt];
                }
            }
            __syncthreads();
            if (tid < 256) {
                float v = 0.0f;
#pragma unroll
                for (int w = 0; w < 8; ++w) v += lf[w * 256 + tid];
                atomicAdd(&stats[tid], v);
            }
        }
    } else {
#pragma unroll
        for (int nt = 0; nt < 8; ++nt) {
            const int c = nt * 16 + m;
            const float sc = ss[c], sh = ss[128 + c];
#pragma unroll
            for (int r = 0; r < 4; ++r) {
                int ea = eb + q * 4 + r;
                if (ea < E) out[(size_t)ea * 128 + c] = fmaxf(acc0[nt][r] * sc + sh, 0.0f);
                int e2 = eb + 16 + q * 4 + r;
                if (e2 < E) out[(size_t)e2 * 128 + c] = fmaxf(acc1[nt][r] * sc + sh, 0.0f);
            }
        }
    }
}

extern "C" void kernel_launch(void* const* d_in, const int* in_sizes, int n_in,
                              void* d_out, int out_size, void* d_ws, size_t ws_size,
                              hipStream_t stream) {
    const float* x     = (const float*)d_in[0];
    const void*  e2e   = d_in[1];
    const float* W     = (const float*)d_in[2];
    // d_in[3] = b : cancels exactly in BatchNorm -> unused
    const float* gamma = (const float*)d_in[4];
    const float* beta  = (const float*)d_in[5];
    float* out = (float*)d_out;
    const int E = in_sizes[0] / 64;

    char* ws = (char*)d_ws;
    const size_t xbBytes = (size_t)E * 128;        // bf16 x
    const size_t cbBytes = (size_t)E * 256;        // bf16 conv result
    const size_t tailBytes = 81920 + 4096;
    const bool bf   = (ws_size >= xbBytes + tailBytes);
    const bool cbok = (ws_size >= xbBytes + cbBytes + tailBytes);

    size_t off = 0;
    short* xbp = (short*)ws;              if (bf)   off += xbBytes;
    short* cbp = (short*)(ws + off);      if (cbok) off += cbBytes;
    short* wfp = (short*)(ws + off);      off += 81920;
    float* stats = (float*)(ws + off);    off += 1024;
    float* ssp   = (float*)(ws + off);    off += 1024;
    int*   flag  = (int*)(ws + off);

    k_setup<<<10, 512, 0, stream>>>(W, wfp, (const int*)e2e, stats, flag);
    const int nb = (E + 255) / 256;
    if (cbok) {
        k_convert<<<2048, 256, 0, stream>>>(x, xbp, E * 8);
        k_conv<0, 0, 1><<<nb, 512, 0, stream>>>(xbp, x, e2e, flag, wfp, stats, ssp, cbp, out, E);
        k_finalize<<<1, 128, 0, stream>>>(stats, gamma, beta, ssp, E);
        k_norm<<<2048, 512, 0, stream>>>(cbp, ssp, out, E * 16);
    } else if (bf) {
        k_convert<<<2048, 256, 0, stream>>>(x, xbp, E * 8);
        k_conv<0, 0, 0><<<nb, 512, 0, stream>>>(xbp, x, e2e, flag, wfp, stats, ssp, cbp, out, E);
        k_finalize<<<1, 128, 0, stream>>>(stats, gamma, beta, ssp, E);
        k_conv<1, 0, 0><<<nb, 512, 0, stream>>>(xbp, x, e2e, flag, wfp, stats, ssp, cbp, out, E);
    } else {
        k_conv<0, 1, 0><<<nb, 512, 0, stream>>>(xbp, x, e2e, flag, wfp, stats, ssp, cbp, out, E);
        k_finalize<<<1, 128, 0, stream>>>(stats, gamma, beta, ssp, E);
        k_conv<1, 1, 0><<<nb, 512, 0, stream>>>(xbp, x, e2e, flag, wfp, stats, ssp, cbp, out, E);
    }
}